// Round 2
// baseline (313.088 us; speedup 1.0000x reference)
//
#include <hip/hip_runtime.h>

#define BATCH 512
#define NN    200
#define SIG1  0.73105857863f   // sigmoid(1)
#define SIG0  0.5f             // sigmoid(0)

// ---------------------------------------------------------------------------
// prep: blocks 0..156: Rs[n][m] = 0.5*(R[n][m]+R[m][n]) + (n==m)   (fp32)
//       block 157:     Wc = W0 @ (W1 @ (W2 @ pw))   [200][2] fp32  (float4 rows)
__global__ __launch_bounds__(256) void prep(
    const float* __restrict__ R,
    const float* __restrict__ W0, const float* __restrict__ W1,
    const float* __restrict__ W2, const float* __restrict__ pw,
    float* __restrict__ Rs, float* __restrict__ Wc) {
    const int blk = blockIdx.x;
    const int tid = threadIdx.x;
    if (blk < 157) {
        int idx = blk * 256 + tid;
        if (idx < NN * NN) {
            int n = idx / NN, m = idx - n * NN;
            Rs[idx] = 0.5f * (R[idx] + R[m * NN + n]) + (n == m ? 1.f : 0.f);
        }
    } else {
        __shared__ float t0[256], t1[256];
        const float* w2r = W2 + tid * 256;
        float a0 = 0.f, a1 = 0.f;
#pragma unroll
        for (int c = 0; c < 64; ++c) {
            float4 w  = *(const float4*)(w2r + c * 4);
            float4 pA = *(const float4*)(pw + c * 8);      // pw rows 4c,4c+1
            float4 pB = *(const float4*)(pw + c * 8 + 4);  // pw rows 4c+2,4c+3
            a0 += w.x * pA.x + w.y * pA.z + w.z * pB.x + w.w * pB.z;
            a1 += w.x * pA.y + w.y * pA.w + w.z * pB.y + w.w * pB.w;
        }
        t0[tid] = a0; t1[tid] = a1;
        __syncthreads();
        const float* w1r = W1 + tid * 256;
        float b0 = 0.f, b1 = 0.f;
#pragma unroll
        for (int h = 0; h < 64; ++h) {
            float4 w = *(const float4*)(w1r + h * 4);
            b0 += w.x * t0[h*4] + w.y * t0[h*4+1] + w.z * t0[h*4+2] + w.w * t0[h*4+3];
            b1 += w.x * t1[h*4] + w.y * t1[h*4+1] + w.z * t1[h*4+2] + w.w * t1[h*4+3];
        }
        __syncthreads();
        t0[tid] = b0; t1[tid] = b1;
        __syncthreads();
        if (tid < NN) {
            const float* w0r = W0 + tid * 256;
            float c0 = 0.f, c1 = 0.f;
#pragma unroll
            for (int o = 0; o < 64; ++o) {
                float4 w = *(const float4*)(w0r + o * 4);
                c0 += w.x * t0[o*4] + w.y * t0[o*4+1] + w.z * t0[o*4+2] + w.w * t0[o*4+3];
                c1 += w.x * t1[o*4] + w.y * t1[o*4+1] + w.z * t1[o*4+2] + w.w * t1[o*4+3];
            }
            Wc[tid * 2 + 0] = c0;
            Wc[tid * 2 + 1] = c1;
        }
    }
}

// ---------------------------------------------------------------------------
// Phase A: load Rs slice into REGISTERS (kept live for B/C), stream adj,
// build adjacency bitmasks, accumulate u-partials. NR compile-time.
template<int NR>
__device__ __forceinline__ void phaseA(const float* __restrict__ adjr,
                                       const float* __restrict__ rsr,
                                       float4 (&rs)[13],
                                       unsigned& m0, unsigned& m1,
                                       unsigned& m2, unsigned& m3,
                                       float4& acc) {
#pragma unroll
    for (int j = 0; j < NR; ++j)
        rs[j] = *(const float4*)(rsr + j * NN);
#pragma unroll
    for (int j = 0; j < NR; ++j) {
        float4 a = *(const float4*)(adjr + j * NN);
        bool t;
        t = a.x > 0.5f; m0 |= (unsigned)t << j; acc.x += rs[j].x * (t ? SIG1 : SIG0);
        t = a.y > 0.5f; m1 |= (unsigned)t << j; acc.y += rs[j].y * (t ? SIG1 : SIG0);
        t = a.z > 0.5f; m2 |= (unsigned)t << j; acc.z += rs[j].z * (t ? SIG1 : SIG0);
        t = a.w > 0.5f; m3 |= (unsigned)t << j; acc.w += rs[j].w * (t ? SIG1 : SIG0);
    }
}

// Phase B/C: acc += M^T x over this thread's slice — ZERO memory loads:
// Rs from registers, adjacency bits from registers, x broadcast from LDS.
template<int NR>
__device__ __forceinline__ void phaseM(const float4 (&rs)[13],
                                       const float* __restrict__ xs, int r0,
                                       unsigned m0, unsigned m1,
                                       unsigned m2, unsigned m3,
                                       float4& acc) {
#pragma unroll
    for (int j = 0; j < NR; ++j) {
        float xn = xs[r0 + j];
        acc.x += rs[j].x * (((m0 >> j) & 1u) ? SIG1 : SIG0) * xn;
        acc.y += rs[j].y * (((m1 >> j) & 1u) ? SIG1 : SIG0) * xn;
        acc.z += rs[j].z * (((m2 >> j) & 1u) ? SIG1 : SIG0) * xn;
        acc.w += rs[j].w * (((m3 >> j) & 1u) ? SIG1 : SIG0) * xn;
    }
}

// Phase D: partial y over this slice's feat rows (13-deep independent loads).
template<int NR>
__device__ __forceinline__ void phaseF(const float* __restrict__ fr,
                                       const float* __restrict__ xs, int r0,
                                       float4& acc) {
#pragma unroll
    for (int j = 0; j < NR; ++j) {
        float4 f = *(const float4*)(fr + j * NN);
        float xn = xs[r0 + j];
        acc.x += f.x * xn; acc.y += f.y * xn;
        acc.z += f.z * xn; acc.w += f.w * xn;
    }
}

// ---------------------------------------------------------------------------
// One 1024-thread block per graph. Rank-1 collapsed MaskGCN, float4 passes:
//   u = M^T 1 ; v = M^T u ; w = M^T v ; y = X^T w ; out = (y·Wc)/N + pb
// Thread (q = tid>>6, c4 = tid&63): rows r0..r0+NR (13/12, wave-uniform),
// cols [4*c4, 4*c4+4) (c4 clamped to 49; duplicate results discarded).
// Rs slice lives in registers across all three M^T phases: B and C issue
// no global loads at all. Only A (adj) and D (feat) touch memory.
__global__ __launch_bounds__(1024, 4) void gcn_main(
    const float* __restrict__ adj, const float* __restrict__ feat,
    const float* __restrict__ Rs, const float* __restrict__ Wc,
    const float* __restrict__ pb, float* __restrict__ out) {
    const int b = blockIdx.x;
    const int tid = threadIdx.x;
    const int c4 = tid & 63;
    const int q  = tid >> 6;                       // 0..15, wave-uniform
    const int cc = (c4 < 50) ? c4 : 49;            // clamp (dup results discarded)
    const int col0 = cc * 4;
    const int r0 = (q < 8) ? 13 * q : 104 + 12 * (q - 8);
    const float* adjb  = adj  + (size_t)b * NN * NN;
    const float* featb = feat + (size_t)b * NN * NN;
    __shared__ float4 us[1024];
    __shared__ float xs[NN];

    float4 rs[13];
    unsigned m0 = 0, m1 = 0, m2 = 0, m3 = 0;
    float4 acc = {0.f, 0.f, 0.f, 0.f};

    // ---- Phase A: u = M^T 1 (adj+Rs streams; Rs captured in registers) ----
    if (q < 8) phaseA<13>(adjb + r0 * NN + col0, Rs + r0 * NN + col0,
                          rs, m0, m1, m2, m3, acc);
    else       phaseA<12>(adjb + r0 * NN + col0, Rs + r0 * NN + col0,
                          rs, m0, m1, m2, m3, acc);
    us[tid] = acc;
    __syncthreads();
    if (tid < 64) {
        float4 s = us[tid];
#pragma unroll
        for (int qq = 1; qq < 16; ++qq) {
            float4 p = us[qq * 64 + tid];
            s.x += p.x; s.y += p.y; s.z += p.z; s.w += p.w;
        }
        if (tid < 50) {
            xs[tid * 4 + 0] = s.x; xs[tid * 4 + 1] = s.y;
            xs[tid * 4 + 2] = s.z; xs[tid * 4 + 3] = s.w;
        }
    }
    __syncthreads();

    // ---- Phase B: v = M^T u  (registers + LDS broadcast only) ----
    acc = (float4){0.f, 0.f, 0.f, 0.f};
    if (q < 8) phaseM<13>(rs, xs, r0, m0, m1, m2, m3, acc);
    else       phaseM<12>(rs, xs, r0, m0, m1, m2, m3, acc);
    us[tid] = acc;
    __syncthreads();
    if (tid < 64) {
        float4 s = us[tid];
#pragma unroll
        for (int qq = 1; qq < 16; ++qq) {
            float4 p = us[qq * 64 + tid];
            s.x += p.x; s.y += p.y; s.z += p.z; s.w += p.w;
        }
        if (tid < 50) {
            xs[tid * 4 + 0] = s.x; xs[tid * 4 + 1] = s.y;
            xs[tid * 4 + 2] = s.z; xs[tid * 4 + 3] = s.w;
        }
    }
    __syncthreads();

    // ---- Phase C: w = M^T v ----
    acc = (float4){0.f, 0.f, 0.f, 0.f};
    if (q < 8) phaseM<13>(rs, xs, r0, m0, m1, m2, m3, acc);
    else       phaseM<12>(rs, xs, r0, m0, m1, m2, m3, acc);
    us[tid] = acc;
    __syncthreads();
    if (tid < 64) {
        float4 s = us[tid];
#pragma unroll
        for (int qq = 1; qq < 16; ++qq) {
            float4 p = us[qq * 64 + tid];
            s.x += p.x; s.y += p.y; s.z += p.z; s.w += p.w;
        }
        if (tid < 50) {
            xs[tid * 4 + 0] = s.x; xs[tid * 4 + 1] = s.y;
            xs[tid * 4 + 2] = s.z; xs[tid * 4 + 3] = s.w;
        }
    }
    __syncthreads();

    // ---- Phase D: partial y over this slice's feat rows ----
    acc = (float4){0.f, 0.f, 0.f, 0.f};
    if (q < 8) phaseF<13>(featb + r0 * NN + col0, xs, r0, acc);
    else       phaseF<12>(featb + r0 * NN + col0, xs, r0, acc);
    us[tid] = acc;
    __syncthreads();

    // ---- Phase E: wave 0 combines y, dots with Wc, reduces, writes out ----
    if (tid < 64) {
        float4 s = us[tid];
#pragma unroll
        for (int qq = 1; qq < 16; ++qq) {
            float4 p = us[qq * 64 + tid];
            s.x += p.x; s.y += p.y; s.z += p.z; s.w += p.w;
        }
        float p0 = 0.f, p1 = 0.f;
        if (tid < 50) {
            int c0i = tid * 4;
            p0 = s.x * Wc[(c0i + 0) * 2] + s.y * Wc[(c0i + 1) * 2]
               + s.z * Wc[(c0i + 2) * 2] + s.w * Wc[(c0i + 3) * 2];
            p1 = s.x * Wc[(c0i + 0) * 2 + 1] + s.y * Wc[(c0i + 1) * 2 + 1]
               + s.z * Wc[(c0i + 2) * 2 + 1] + s.w * Wc[(c0i + 3) * 2 + 1];
        }
#pragma unroll
        for (int off = 32; off > 0; off >>= 1) {
            p0 += __shfl_down(p0, off);
            p1 += __shfl_down(p1, off);
        }
        if (tid == 0) {
            out[b * 2 + 0] = p0 * (1.f / NN) + pb[0];
            out[b * 2 + 1] = p1 * (1.f / NN) + pb[1];
        }
    }
}

// ---------------------------------------------------------------------------
extern "C" void kernel_launch(void* const* d_in, const int* in_sizes, int n_in,
                              void* d_out, int out_size, void* d_ws, size_t ws_size,
                              hipStream_t stream) {
    const float* adj  = (const float*)d_in[0];
    const float* feat = (const float*)d_in[1];
    const float* R    = (const float*)d_in[2];
    const float* W0   = (const float*)d_in[3];
    const float* W1   = (const float*)d_in[4];
    const float* W2   = (const float*)d_in[5];
    const float* pw   = (const float*)d_in[6];
    const float* pb   = (const float*)d_in[7];

    char* ws = (char*)d_ws;
    float* Rs = (float*)(ws);             // 160,000 B
    float* Wc = (float*)(ws + 160000);    // 1,600 B

    prep<<<158, 256, 0, stream>>>(R, W0, W1, W2, pw, Rs, Wc);
    gcn_main<<<BATCH, 1024, 0, stream>>>(adj, feat, Rs, Wc, pb, (float*)d_out);
}

// Round 3
// 256.326 us; speedup vs baseline: 1.2214x; 1.2214x over previous
//
#include <hip/hip_runtime.h>

#define BATCH 512
#define NN    200
#define SIG1  0.73105857863f   // sigmoid(1)
#define SIG0  0.5f             // sigmoid(0)

typedef unsigned int uint;

// ---------------------------------------------------------------------------
// Pack NR rows of one column-quad of adj into 13-bit masks.
template<int NR>
__device__ __forceinline__ void packRows(const float* __restrict__ adjr,
                                         uint& m0, uint& m1, uint& m2, uint& m3) {
#pragma unroll
    for (int j = 0; j < NR; ++j) {
        float4 a = *(const float4*)(adjr + j * NN);
        m0 |= (uint)(a.x > 0.5f) << j;
        m1 |= (uint)(a.y > 0.5f) << j;
        m2 |= (uint)(a.z > 0.5f) << j;
        m3 |= (uint)(a.w > 0.5f) << j;
    }
}

// ---------------------------------------------------------------------------
// prep1 (one launch, independent block roles):
//   blocks 0..511   : pack adj[b] -> 13-bit masks in gcn's (q,c4) layout (uint2)
//   blocks 512..551 : Rs[n][m] = 0.5*(R[n][m]+R[m][n]) + (n==m)
//   block  552      : Wc = W0 @ (W1 @ (W2 @ pw))  [200][2], 4 threads/row
// The serial-ish Wc chain hides under the 82 MB adj pack stream.
__global__ __launch_bounds__(1024) void prep1(
    const float* __restrict__ adj, const float* __restrict__ R,
    const float* __restrict__ W0, const float* __restrict__ W1,
    const float* __restrict__ W2, const float* __restrict__ pw,
    float* __restrict__ Rs, float* __restrict__ Wc, uint2* __restrict__ bits) {
    const int blk = blockIdx.x;
    const int tid = threadIdx.x;

    if (blk < BATCH) {                       // ---- pack adj ----
        const int c4 = tid & 63;
        const int q  = tid >> 6;
        if (c4 < 50) {
            const int col0 = c4 * 4;
            const int r0 = (q < 8) ? 13 * q : 104 + 12 * (q - 8);
            const float* adjr = adj + (size_t)blk * NN * NN + r0 * NN + col0;
            uint m0 = 0, m1 = 0, m2 = 0, m3 = 0;
            if (q < 8) packRows<13>(adjr, m0, m1, m2, m3);
            else       packRows<12>(adjr, m0, m1, m2, m3);
            uint2 v;
            v.x = m0 | (m1 << 13);
            v.y = m2 | (m3 << 13);
            bits[(size_t)blk * 800 + q * 50 + c4] = v;
        }
    } else if (blk < BATCH + 40) {           // ---- Rs symmetrize ----
        int idx = (blk - BATCH) * 1024 + tid;
        if (idx < NN * NN) {
            int n = idx / NN, m = idx - n * NN;
            Rs[idx] = 0.5f * (R[idx] + R[m * NN + n]) + (n == m ? 1.f : 0.f);
        }
    } else {                                  // ---- Wc chain ----
        __shared__ float t0[256], t1[256], u0[256], u1[256];
        const int h  = tid >> 2;              // 0..255
        const int t4 = tid & 3;               // 64-term slice per thread
        {   // stage 1: t = W2 @ pw
            const float* w2r = W2 + h * 256 + t4 * 64;
            const float* pwr = pw + t4 * 128;
            float a0 = 0.f, a1 = 0.f;
#pragma unroll
            for (int k = 0; k < 16; ++k) {
                float4 w  = *(const float4*)(w2r + k * 4);
                float4 pA = *(const float4*)(pwr + k * 8);
                float4 pB = *(const float4*)(pwr + k * 8 + 4);
                a0 += w.x * pA.x + w.y * pA.z + w.z * pB.x + w.w * pB.z;
                a1 += w.x * pA.y + w.y * pA.w + w.z * pB.y + w.w * pB.w;
            }
            a0 += __shfl_xor(a0, 1); a0 += __shfl_xor(a0, 2);
            a1 += __shfl_xor(a1, 1); a1 += __shfl_xor(a1, 2);
            if (t4 == 0) { t0[h] = a0; t1[h] = a1; }
        }
        __syncthreads();
        {   // stage 2: u = W1 @ t
            const float* w1r = W1 + h * 256 + t4 * 64;
            float b0 = 0.f, b1 = 0.f;
#pragma unroll
            for (int k = 0; k < 16; ++k) {
                float4 w = *(const float4*)(w1r + k * 4);
                int c = t4 * 64 + k * 4;
                b0 += w.x * t0[c] + w.y * t0[c+1] + w.z * t0[c+2] + w.w * t0[c+3];
                b1 += w.x * t1[c] + w.y * t1[c+1] + w.z * t1[c+2] + w.w * t1[c+3];
            }
            b0 += __shfl_xor(b0, 1); b0 += __shfl_xor(b0, 2);
            b1 += __shfl_xor(b1, 1); b1 += __shfl_xor(b1, 2);
            if (t4 == 0) { u0[h] = b0; u1[h] = b1; }
        }
        __syncthreads();
        if (h < NN) {   // stage 3: Wc = W0 @ u
            const float* w0r = W0 + h * 256 + t4 * 64;
            float c0 = 0.f, c1 = 0.f;
#pragma unroll
            for (int k = 0; k < 16; ++k) {
                float4 w = *(const float4*)(w0r + k * 4);
                int c = t4 * 64 + k * 4;
                c0 += w.x * u0[c] + w.y * u0[c+1] + w.z * u0[c+2] + w.w * u0[c+3];
                c1 += w.x * u1[c] + w.y * u1[c+1] + w.z * u1[c+2] + w.w * u1[c+3];
            }
            c0 += __shfl_xor(c0, 1); c0 += __shfl_xor(c0, 2);
            c1 += __shfl_xor(c1, 1); c1 += __shfl_xor(c1, 2);
            if (t4 == 0) { Wc[h * 2] = c0; Wc[h * 2 + 1] = c1; }
        }
    }
}

// ---------------------------------------------------------------------------
// prep_fw: FW[b][n][:] = feat[b][n][:] @ Wc   (pure 82 MB stream, 4 thr/row)
__global__ __launch_bounds__(1024) void prep_fw(
    const float* __restrict__ feat, const float* __restrict__ Wc,
    float* __restrict__ FW) {
    const int b = blockIdx.x;
    const int tid = threadIdx.x;
    __shared__ float WcL[2 * NN];
    if (tid < 100) *(float4*)(WcL + tid * 4) = *(const float4*)(Wc + tid * 4);
    __syncthreads();
    const int t4 = tid & 3, nrow = tid >> 2;   // 4 threads per row
    if (nrow < NN) {
        const float* fr = feat + (size_t)b * NN * NN + nrow * NN;
        float p0 = 0.f, p1 = 0.f;
#pragma unroll
        for (int k = 0; k < 12; ++k) {
            const int cidx = t4 + k * 4;
            float4 f  = *(const float4*)(fr + cidx * 4);
            float4 wa = *(const float4*)(WcL + cidx * 8);
            float4 wb = *(const float4*)(WcL + cidx * 8 + 4);
            p0 += f.x * wa.x + f.y * wa.z + f.z * wb.x + f.w * wb.z;
            p1 += f.x * wa.y + f.y * wa.w + f.z * wb.y + f.w * wb.w;
        }
        if (t4 < 2) {                          // chunks 48,49
            const int cidx = t4 + 48;
            float4 f  = *(const float4*)(fr + cidx * 4);
            float4 wa = *(const float4*)(WcL + cidx * 8);
            float4 wb = *(const float4*)(WcL + cidx * 8 + 4);
            p0 += f.x * wa.x + f.y * wa.z + f.z * wb.x + f.w * wb.z;
            p1 += f.x * wa.y + f.y * wa.w + f.z * wb.y + f.w * wb.w;
        }
        p0 += __shfl_down(p0, 1); p0 += __shfl_down(p0, 2);
        p1 += __shfl_down(p1, 1); p1 += __shfl_down(p1, 2);
        if (t4 == 0) {
            FW[(size_t)b * 2 * NN + nrow * 2]     = p0;
            FW[(size_t)b * 2 * NN + nrow * 2 + 1] = p1;
        }
    }
}

// ---------------------------------------------------------------------------
// Phase A: u partial from Rs (L2-hot) + register bitmasks.
template<int NR>
__device__ __forceinline__ void phaseU(const float* __restrict__ rsr,
                                       uint m0, uint m1, uint m2, uint m3,
                                       float4& acc) {
#pragma unroll
    for (int j = 0; j < NR; ++j) {
        float4 r = *(const float4*)(rsr + j * NN);
        acc.x += r.x * (((m0 >> j) & 1u) ? SIG1 : SIG0);
        acc.y += r.y * (((m1 >> j) & 1u) ? SIG1 : SIG0);
        acc.z += r.z * (((m2 >> j) & 1u) ? SIG1 : SIG0);
        acc.w += r.w * (((m3 >> j) & 1u) ? SIG1 : SIG0);
    }
}

// Phase B/C: acc += M^T x (Rs from L2, bits in regs, x broadcast from LDS).
template<int NR>
__device__ __forceinline__ void phaseM(const float* __restrict__ rsr,
                                       const float* __restrict__ xs, int r0,
                                       uint m0, uint m1, uint m2, uint m3,
                                       float4& acc) {
#pragma unroll
    for (int j = 0; j < NR; ++j) {
        float4 r = *(const float4*)(rsr + j * NN);
        float xn = xs[r0 + j];
        acc.x += r.x * (((m0 >> j) & 1u) ? SIG1 : SIG0) * xn;
        acc.y += r.y * (((m1 >> j) & 1u) ? SIG1 : SIG0) * xn;
        acc.z += r.z * (((m2 >> j) & 1u) ? SIG1 : SIG0) * xn;
        acc.w += r.w * (((m3 >> j) & 1u) ? SIG1 : SIG0) * xn;
    }
}

// ---------------------------------------------------------------------------
// gcn_main: no big streams left. Per block: bits (8 B/thread), Rs (L2-hot,
// 3 passes), FW (1.6 KB). u = M^T 1 ; v = M^T u ; w = M^T v ; out = w·FW/N+pb.
// Final dot folded into phase C's wave-0 reduction: 5 barriers total.
__global__ __launch_bounds__(1024) void gcn_main(
    const uint2* __restrict__ bits, const float* __restrict__ Rs,
    const float* __restrict__ FW, const float* __restrict__ pb,
    float* __restrict__ out) {
    const int b = blockIdx.x;
    const int tid = threadIdx.x;
    const int c4 = tid & 63;
    const int q  = tid >> 6;                       // 0..15, wave-uniform
    const int cc = (c4 < 50) ? c4 : 49;            // clamp (dups discarded)
    const int col0 = cc * 4;
    const int r0 = (q < 8) ? 13 * q : 104 + 12 * (q - 8);
    const float* rsr = Rs + r0 * NN + col0;
    __shared__ float4 us[1024];
    __shared__ float xs[NN];

    const uint2 mw = bits[(size_t)b * 800 + q * 50 + cc];
    const uint m0 = mw.x & 0x1FFFu, m1 = mw.x >> 13;
    const uint m2 = mw.y & 0x1FFFu, m3 = mw.y >> 13;

    // ---- Phase A: u = M^T 1 ----
    float4 acc = {0.f, 0.f, 0.f, 0.f};
    if (q < 8) phaseU<13>(rsr, m0, m1, m2, m3, acc);
    else       phaseU<12>(rsr, m0, m1, m2, m3, acc);
    us[tid] = acc;
    __syncthreads();
    if (tid < 64) {
        float4 s = us[tid];
#pragma unroll
        for (int qq = 1; qq < 16; ++qq) {
            float4 p = us[qq * 64 + tid];
            s.x += p.x; s.y += p.y; s.z += p.z; s.w += p.w;
        }
        if (tid < 50) {
            xs[tid * 4 + 0] = s.x; xs[tid * 4 + 1] = s.y;
            xs[tid * 4 + 2] = s.z; xs[tid * 4 + 3] = s.w;
        }
    }
    __syncthreads();

    // ---- Phase B: v = M^T u ----
    acc = (float4){0.f, 0.f, 0.f, 0.f};
    if (q < 8) phaseM<13>(rsr, xs, r0, m0, m1, m2, m3, acc);
    else       phaseM<12>(rsr, xs, r0, m0, m1, m2, m3, acc);
    us[tid] = acc;
    __syncthreads();
    if (tid < 64) {
        float4 s = us[tid];
#pragma unroll
        for (int qq = 1; qq < 16; ++qq) {
            float4 p = us[qq * 64 + tid];
            s.x += p.x; s.y += p.y; s.z += p.z; s.w += p.w;
        }
        if (tid < 50) {
            xs[tid * 4 + 0] = s.x; xs[tid * 4 + 1] = s.y;
            xs[tid * 4 + 2] = s.z; xs[tid * 4 + 3] = s.w;
        }
    }
    __syncthreads();

    // ---- Phase C: w = M^T v, fused with final dot out = (w·FW)/N + pb ----
    acc = (float4){0.f, 0.f, 0.f, 0.f};
    if (q < 8) phaseM<13>(rsr, xs, r0, m0, m1, m2, m3, acc);
    else       phaseM<12>(rsr, xs, r0, m0, m1, m2, m3, acc);
    us[tid] = acc;
    __syncthreads();
    if (tid < 64) {
        float4 s = us[tid];
#pragma unroll
        for (int qq = 1; qq < 16; ++qq) {
            float4 p = us[qq * 64 + tid];
            s.x += p.x; s.y += p.y; s.z += p.z; s.w += p.w;
        }
        float p0 = 0.f, p1 = 0.f;
        if (tid < 50) {
            const float2* fw2 = (const float2*)(FW + (size_t)b * 2 * NN);
            float2 fa = fw2[tid * 4 + 0], fb = fw2[tid * 4 + 1];
            float2 fc = fw2[tid * 4 + 2], fd = fw2[tid * 4 + 3];
            p0 = s.x * fa.x + s.y * fb.x + s.z * fc.x + s.w * fd.x;
            p1 = s.x * fa.y + s.y * fb.y + s.z * fc.y + s.w * fd.y;
        }
#pragma unroll
        for (int off = 32; off > 0; off >>= 1) {
            p0 += __shfl_down(p0, off);
            p1 += __shfl_down(p1, off);
        }
        if (tid == 0) {
            out[b * 2 + 0] = p0 * (1.f / NN) + pb[0];
            out[b * 2 + 1] = p1 * (1.f / NN) + pb[1];
        }
    }
}

// ---------------------------------------------------------------------------
extern "C" void kernel_launch(void* const* d_in, const int* in_sizes, int n_in,
                              void* d_out, int out_size, void* d_ws, size_t ws_size,
                              hipStream_t stream) {
    const float* adj  = (const float*)d_in[0];
    const float* feat = (const float*)d_in[1];
    const float* R    = (const float*)d_in[2];
    const float* W0   = (const float*)d_in[3];
    const float* W1   = (const float*)d_in[4];
    const float* W2   = (const float*)d_in[5];
    const float* pw   = (const float*)d_in[6];
    const float* pb   = (const float*)d_in[7];

    // workspace: Rs 160,000 | Wc 1,600 | FW 819,200 | bits 3,276,800  = 4.26 MB
    char* ws = (char*)d_ws;
    float* Rs   = (float*)(ws);
    float* Wc   = (float*)(ws + 160000);
    float* FW   = (float*)(ws + 161600);
    uint2* bits = (uint2*)(ws + 980800);

    prep1<<<BATCH + 41, 1024, 0, stream>>>(adj, R, W0, W1, W2, pw, Rs, Wc, bits);
    prep_fw<<<BATCH, 1024, 0, stream>>>(feat, Wc, FW);
    gcn_main<<<BATCH, 1024, 0, stream>>>(bits, Rs, FW, pb, (float*)d_out);
}

// Round 4
// 245.199 us; speedup vs baseline: 1.2769x; 1.0454x over previous
//
#include <hip/hip_runtime.h>

#define BATCH 512
#define NN    200
#define SIG1  0.73105857863f   // sigmoid(1)
#define SIG0  0.5f             // sigmoid(0)

// ---------------------------------------------------------------------------
// prep_small: blocks 0..39: Rs[n][m] = 0.5*(R[n][m]+R[m][n]) + (n==m)
//             block  40   : Wc = W0 @ (W1 @ (W2 @ pw)) [200][2], 4 thr/row,
//                           float4 rows (parallel chain — no serial block).
__global__ __launch_bounds__(1024) void prep_small(
    const float* __restrict__ R,
    const float* __restrict__ W0, const float* __restrict__ W1,
    const float* __restrict__ W2, const float* __restrict__ pw,
    float* __restrict__ Rs, float* __restrict__ Wc) {
    const int blk = blockIdx.x;
    const int tid = threadIdx.x;

    if (blk < 40) {                           // ---- Rs symmetrize ----
        int idx = blk * 1024 + tid;
        if (idx < NN * NN) {
            int n = idx / NN, m = idx - n * NN;
            Rs[idx] = 0.5f * (R[idx] + R[m * NN + n]) + (n == m ? 1.f : 0.f);
        }
    } else {                                  // ---- Wc chain ----
        __shared__ float t0[256], t1[256], u0[256], u1[256];
        const int h  = tid >> 2;              // 0..255
        const int t4 = tid & 3;               // 64-term slice per thread
        {   // stage 1: t = W2 @ pw
            const float* w2r = W2 + h * 256 + t4 * 64;
            const float* pwr = pw + t4 * 128;
            float a0 = 0.f, a1 = 0.f;
#pragma unroll
            for (int k = 0; k < 16; ++k) {
                float4 w  = *(const float4*)(w2r + k * 4);
                float4 pA = *(const float4*)(pwr + k * 8);
                float4 pB = *(const float4*)(pwr + k * 8 + 4);
                a0 += w.x * pA.x + w.y * pA.z + w.z * pB.x + w.w * pB.z;
                a1 += w.x * pA.y + w.y * pA.w + w.z * pB.y + w.w * pB.w;
            }
            a0 += __shfl_xor(a0, 1); a0 += __shfl_xor(a0, 2);
            a1 += __shfl_xor(a1, 1); a1 += __shfl_xor(a1, 2);
            if (t4 == 0) { t0[h] = a0; t1[h] = a1; }
        }
        __syncthreads();
        {   // stage 2: u = W1 @ t
            const float* w1r = W1 + h * 256 + t4 * 64;
            float b0 = 0.f, b1 = 0.f;
#pragma unroll
            for (int k = 0; k < 16; ++k) {
                float4 w = *(const float4*)(w1r + k * 4);
                int c = t4 * 64 + k * 4;
                b0 += w.x * t0[c] + w.y * t0[c+1] + w.z * t0[c+2] + w.w * t0[c+3];
                b1 += w.x * t1[c] + w.y * t1[c+1] + w.z * t1[c+2] + w.w * t1[c+3];
            }
            b0 += __shfl_xor(b0, 1); b0 += __shfl_xor(b0, 2);
            b1 += __shfl_xor(b1, 1); b1 += __shfl_xor(b1, 2);
            if (t4 == 0) { u0[h] = b0; u1[h] = b1; }
        }
        __syncthreads();
        if (h < NN) {   // stage 3: Wc = W0 @ u
            const float* w0r = W0 + h * 256 + t4 * 64;
            float c0 = 0.f, c1 = 0.f;
#pragma unroll
            for (int k = 0; k < 16; ++k) {
                float4 w = *(const float4*)(w0r + k * 4);
                int c = t4 * 64 + k * 4;
                c0 += w.x * u0[c] + w.y * u0[c+1] + w.z * u0[c+2] + w.w * u0[c+3];
                c1 += w.x * u1[c] + w.y * u1[c+1] + w.z * u1[c+2] + w.w * u1[c+3];
            }
            c0 += __shfl_xor(c0, 1); c0 += __shfl_xor(c0, 2);
            c1 += __shfl_xor(c1, 1); c1 += __shfl_xor(c1, 2);
            if (t4 == 0) { Wc[h * 2] = c0; Wc[h * 2 + 1] = c1; }
        }
    }
}

// ---------------------------------------------------------------------------
// One 1024-thread block per graph. Rank-1 collapsed MaskGCN, float4 passes:
//   u = M^T 1 ; v = M^T u ; w = M^T v ; y = X^T w ; out = (y·Wc)/N + pb
// Thread (q = tid>>6, c4 = tid&63): rows r0..r0+nr (12/13, wave-uniform),
// cols [4*c4, 4*c4+4) (c4 clamped to 49; duplicate results discarded).
// adj binary -> sigmoid in {SIG0, SIG1}; per-col row-slice bitmask in uint.
// [Verbatim r0 kernel: measured 66.5 us on MI355X.]
__global__ __launch_bounds__(1024) void gcn_main(
    const float* __restrict__ adj, const float* __restrict__ feat,
    const float* __restrict__ Rs, const float* __restrict__ Wc,
    const float* __restrict__ pb, float* __restrict__ out) {
    const int b = blockIdx.x;
    const int tid = threadIdx.x;
    const int c4 = tid & 63;
    const int q  = tid >> 6;                       // 0..15, wave-uniform
    const int cc = (c4 < 50) ? c4 : 49;            // clamp (dup results discarded)
    const int col0 = cc * 4;
    const int r0 = (q < 8) ? 13 * q : 104 + 12 * (q - 8);
    const int nr = (q < 8) ? 13 : 12;              // wave-uniform trip count
    const float* adjb  = adj  + (size_t)b * NN * NN;
    const float* featb = feat + (size_t)b * NN * NN;
    __shared__ float4 us[1024];
    __shared__ float xs[NN];

    // Phase A: one float4 pass over adj slice -> bitmasks + partial u
    uint m0 = 0, m1 = 0, m2 = 0, m3 = 0;
    float4 acc = {0.f, 0.f, 0.f, 0.f};
#pragma unroll 4
    for (int j = 0; j < nr; ++j) {
        int n = r0 + j;
        float4 a = *(const float4*)(adjb + n * NN + col0);
        float4 r = *(const float4*)(Rs   + n * NN + col0);
        bool t;
        t = a.x > 0.5f; m0 |= (uint)t << j; acc.x += r.x * (t ? SIG1 : SIG0);
        t = a.y > 0.5f; m1 |= (uint)t << j; acc.y += r.y * (t ? SIG1 : SIG0);
        t = a.z > 0.5f; m2 |= (uint)t << j; acc.z += r.z * (t ? SIG1 : SIG0);
        t = a.w > 0.5f; m3 |= (uint)t << j; acc.w += r.w * (t ? SIG1 : SIG0);
    }
    us[tid] = acc;
    __syncthreads();
    if (tid < 64) {
        float4 s = us[tid];
#pragma unroll
        for (int qq = 1; qq < 16; ++qq) {
            float4 p = us[qq * 64 + tid];
            s.x += p.x; s.y += p.y; s.z += p.z; s.w += p.w;
        }
        if (tid < 50) {
            xs[tid * 4 + 0] = s.x; xs[tid * 4 + 1] = s.y;
            xs[tid * 4 + 2] = s.z; xs[tid * 4 + 3] = s.w;
        }
    }
    __syncthreads();

    // Phase B: v = M^T u  (Rs from L2, masks in regs, xs broadcast from LDS)
    acc = (float4){0.f, 0.f, 0.f, 0.f};
#pragma unroll 4
    for (int j = 0; j < nr; ++j) {
        int n = r0 + j;
        float4 r = *(const float4*)(Rs + n * NN + col0);
        float xn = xs[n];
        acc.x += r.x * (((m0 >> j) & 1u) ? SIG1 : SIG0) * xn;
        acc.y += r.y * (((m1 >> j) & 1u) ? SIG1 : SIG0) * xn;
        acc.z += r.z * (((m2 >> j) & 1u) ? SIG1 : SIG0) * xn;
        acc.w += r.w * (((m3 >> j) & 1u) ? SIG1 : SIG0) * xn;
    }
    us[tid] = acc;
    __syncthreads();
    if (tid < 64) {
        float4 s = us[tid];
#pragma unroll
        for (int qq = 1; qq < 16; ++qq) {
            float4 p = us[qq * 64 + tid];
            s.x += p.x; s.y += p.y; s.z += p.z; s.w += p.w;
        }
        if (tid < 50) {
            xs[tid * 4 + 0] = s.x; xs[tid * 4 + 1] = s.y;
            xs[tid * 4 + 2] = s.z; xs[tid * 4 + 3] = s.w;
        }
    }
    __syncthreads();

    // Phase C: w = M^T v
    acc = (float4){0.f, 0.f, 0.f, 0.f};
#pragma unroll 4
    for (int j = 0; j < nr; ++j) {
        int n = r0 + j;
        float4 r = *(const float4*)(Rs + n * NN + col0);
        float xn = xs[n];
        acc.x += r.x * (((m0 >> j) & 1u) ? SIG1 : SIG0) * xn;
        acc.y += r.y * (((m1 >> j) & 1u) ? SIG1 : SIG0) * xn;
        acc.z += r.z * (((m2 >> j) & 1u) ? SIG1 : SIG0) * xn;
        acc.w += r.w * (((m3 >> j) & 1u) ? SIG1 : SIG0) * xn;
    }
    us[tid] = acc;
    __syncthreads();
    if (tid < 64) {
        float4 s = us[tid];
#pragma unroll
        for (int qq = 1; qq < 16; ++qq) {
            float4 p = us[qq * 64 + tid];
            s.x += p.x; s.y += p.y; s.z += p.z; s.w += p.w;
        }
        if (tid < 50) {
            xs[tid * 4 + 0] = s.x; xs[tid * 4 + 1] = s.y;
            xs[tid * 4 + 2] = s.z; xs[tid * 4 + 3] = s.w;
        }
    }
    __syncthreads();

    // Phase D: partial y over this slice's feat rows
    acc = (float4){0.f, 0.f, 0.f, 0.f};
#pragma unroll 4
    for (int j = 0; j < nr; ++j) {
        int n = r0 + j;
        float4 f = *(const float4*)(featb + n * NN + col0);
        float xn = xs[n];
        acc.x += f.x * xn; acc.y += f.y * xn;
        acc.z += f.z * xn; acc.w += f.w * xn;
    }
    us[tid] = acc;
    __syncthreads();

    // Phase E: wave 0 combines y, dots with Wc, reduces, writes out
    if (tid < 64) {
        float4 s = us[tid];
#pragma unroll
        for (int qq = 1; qq < 16; ++qq) {
            float4 p = us[qq * 64 + tid];
            s.x += p.x; s.y += p.y; s.z += p.z; s.w += p.w;
        }
        float p0 = 0.f, p1 = 0.f;
        if (tid < 50) {
            int c0i = tid * 4;
            p0 = s.x * Wc[(c0i + 0) * 2] + s.y * Wc[(c0i + 1) * 2]
               + s.z * Wc[(c0i + 2) * 2] + s.w * Wc[(c0i + 3) * 2];
            p1 = s.x * Wc[(c0i + 0) * 2 + 1] + s.y * Wc[(c0i + 1) * 2 + 1]
               + s.z * Wc[(c0i + 2) * 2 + 1] + s.w * Wc[(c0i + 3) * 2 + 1];
        }
#pragma unroll
        for (int off = 32; off > 0; off >>= 1) {
            p0 += __shfl_down(p0, off);
            p1 += __shfl_down(p1, off);
        }
        if (tid == 0) {
            out[b * 2 + 0] = p0 * (1.f / NN) + pb[0];
            out[b * 2 + 1] = p1 * (1.f / NN) + pb[1];
        }
    }
}

// ---------------------------------------------------------------------------
extern "C" void kernel_launch(void* const* d_in, const int* in_sizes, int n_in,
                              void* d_out, int out_size, void* d_ws, size_t ws_size,
                              hipStream_t stream) {
    const float* adj  = (const float*)d_in[0];
    const float* feat = (const float*)d_in[1];
    const float* R    = (const float*)d_in[2];
    const float* W0   = (const float*)d_in[3];
    const float* W1   = (const float*)d_in[4];
    const float* W2   = (const float*)d_in[5];
    const float* pw   = (const float*)d_in[6];
    const float* pb   = (const float*)d_in[7];

    char* ws = (char*)d_ws;
    float* Rs = (float*)(ws);             // 160,000 B
    float* Wc = (float*)(ws + 160000);    // 1,600 B

    prep_small<<<41, 1024, 0, stream>>>(R, W0, W1, W2, pw, Rs, Wc);
    gcn_main<<<BATCH, 1024, 0, stream>>>(adj, feat, Rs, Wc, pb, (float*)d_out);
}